// Round 16
// baseline (1626.064 us; speedup 1.0000x reference)
//
#include <hip/hip_runtime.h>

#define NROWS 8192
#define NG    12972
#define H     1000
#define NP    1024   // padded hidden width
#define KX    288    // padded hints width (multiple of 32)
#define OCP   256    // padded output cols
#define OC    130
#define EPSBN 1e-5f
#define MBLK  (NROWS / 128)   // 64 row-blocks => 64 stat partials

typedef __attribute__((ext_vector_type(8))) _Float16 f16x8;
typedef __attribute__((ext_vector_type(8))) unsigned short u16x8;
typedef __attribute__((ext_vector_type(4))) float f32x4;

__device__ __forceinline__ float lrelu(float x) { return x >= 0.f ? x : 0.2f * x; }

// ---------------- prep: transpose fp32 -> fp16, B^T layout ----------------
__global__ void transpose_f16(const float* __restrict__ src, int R, int C, int srcStride,
                              _Float16* __restrict__ dst, int Rp, int Cp) {
    __shared__ float tile[32][33];
    int k0 = blockIdx.x * 32;
    int n0 = blockIdx.y * 32;
    int tx = threadIdx.x, ty = threadIdx.y;  // 32 x 8
#pragma unroll
    for (int i = 0; i < 32; i += 8) {
        int k = k0 + ty + i, n = n0 + tx;
        tile[ty + i][tx] = (k < R && n < C) ? src[(size_t)k * srcStride + n] : 0.f;
    }
    __syncthreads();
#pragma unroll
    for (int i = 0; i < 32; i += 8) {
        int n = n0 + ty + i, k = k0 + tx;
        if (n < Cp && k < Rp) dst[(size_t)n * Rp + k] = (_Float16)tile[tx][ty + i];
    }
}

__global__ void prep_bias(const float* __restrict__ W0, const float* __restrict__ b0,
                          const float* __restrict__ bh, const float* __restrict__ bout,
                          float* __restrict__ b0p, float* __restrict__ w0t,
                          float* __restrict__ bhp, float* __restrict__ boutp) {
    int i = blockIdx.x * 256 + threadIdx.x;
    if (i < 1024) { b0p[i] = (i < H) ? b0[i] : 0.f; return; }
    i -= 1024;
    if (i < 6 * 1024) {
        int t = i >> 10, n = i & 1023;
        w0t[i] = (n < H) ? W0[(size_t)(286 + t) * H + n] : 0.f;
        return;
    }
    i -= 6 * 1024;
    if (i < 3 * 1024) {
        int l = i >> 10, n = i & 1023;
        bhp[i] = (n < H) ? bh[l * H + n] : 0.f;
        return;
    }
    i -= 3 * 1024;
    if (i < OCP) { boutp[i] = (i < OC) ? bout[i] : 0.f; }
}

// gl: letters (for hint update). glp: packed softmax offsets letter*5+p (5 bytes in uint2).
__global__ void prep_guess_letters(const float* __restrict__ gm, unsigned char* __restrict__ gl,
                                   uint2* __restrict__ glp) {
    int g = blockIdx.x * blockDim.x + threadIdx.x;
    if (g >= NG) return;
    unsigned off[5];
    for (int p = 0; p < 5; ++p) {
        int letter = 0;
        for (int c = 0; c < 26; ++c)
            if (gm[(size_t)g * 130 + c * 5 + p] > 0.5f) { letter = c; break; }
        gl[g * 8 + p] = (unsigned char)letter;
        off[p] = (unsigned)(letter * 5 + p);
    }
    gl[g * 8 + 5] = gl[g * 8 + 6] = gl[g * 8 + 7] = 0;
    glp[g] = make_uint2(off[0] | (off[1] << 8) | (off[2] << 16) | (off[3] << 24), off[4]);
}

__global__ void prep_sol_letters(const float* __restrict__ sols, unsigned char* __restrict__ sl,
                                 unsigned int* __restrict__ msk) {
    int r = blockIdx.x * blockDim.x + threadIdx.x;
    if (r >= NROWS) return;
    unsigned int m = 0;
    for (int p = 0; p < 5; ++p) {
        int letter = 0;
        for (int c = 0; c < 26; ++c)
            if (sols[(size_t)r * 130 + c * 5 + p] > 0.5f) { letter = c; break; }
        sl[r * 8 + p] = (unsigned char)letter;
        m |= 1u << letter;
    }
    sl[r * 8 + 5] = sl[r * 8 + 6] = sl[r * 8 + 7] = 0;
    msk[r] = m;
}

__global__ void init_state(unsigned short* __restrict__ hX, float* __restrict__ scores,
                           int* __restrict__ solvedf, float* __restrict__ lossacc,
                           int* __restrict__ cnt243) {
    int i = blockIdx.x * blockDim.x + threadIdx.x;
    if (i < NROWS * KX) hX[i] = 0;
    if (i < NROWS) { scores[i] = 7.f; solvedf[i] = 0; }
    if (i == 0) lossacc[0] = 0.f;
    if (i < 256) cnt243[i] = 0;
}

// ---------------- GEMM fp16: C = A*B^T + bias, fused column stats ----------------
// 128x128 tile, 4 waves (2x2), templated BK, single LDS buffer, global_load_lds staging.
// WEIGHTED: per-row weights for column stats (turn-1 dedup path).
template <int BK, bool HALF_C, bool WEIGHTED>
__global__ __launch_bounds__(256, 2) void gemm_f16(
    const _Float16* __restrict__ A, int lda,
    const _Float16* __restrict__ B, int ldb,
    void* __restrict__ Cv, int ldc,
    const float* __restrict__ bias1, const float* __restrict__ bias2, int kiter,
    float* __restrict__ pS, float* __restrict__ pS2, const float* __restrict__ wrow) {
    constexpr int NCH = BK / 8;
    constexpr int ABYTES = 256 * BK;
    constexpr int KSUB = BK / 32;
    constexpr int AW = 16 * BK;
    __shared__ char smem[512 * BK];
    const int tid = threadIdx.x;
    const int lane = tid & 63;
    const int rowBase = blockIdx.x * 128;
    const int colBase = blockIdx.y * 128;
    const int wm = (tid >> 6) & 1;
    const int wn = tid >> 7;

    const _Float16* gsrc[NCH];
    int ldsuni[NCH];
#pragma unroll
    for (int i = 0; i < NCH; ++i) {
        int w = i * 256 + tid;
        const _Float16* plane;
        int off;
        if (w < AW) {
            int r = w & 127, kb = w >> 7;
            plane = A;
            off = (rowBase + r) * lda + kb * 8;
        } else {
            int v = w - AW;
            int col = v & 127, kb = v >> 7;
            plane = B;
            off = (colBase + col) * ldb + kb * 8;
        }
        gsrc[i] = plane + off;
        ldsuni[i] = (i * 256 + (tid & ~63)) * 16;
    }

    f32x4 acc[4][4];
    const f32x4 z = {0.f, 0.f, 0.f, 0.f};
#pragma unroll
    for (int m = 0; m < 4; ++m)
#pragma unroll
        for (int n = 0; n < 4; ++n) acc[m][n] = z;

    const int aro = (lane >> 4) * 2048 + (wm * 64 + (lane & 15)) * 16;
    const int bco = ABYTES + (lane >> 4) * 2048 + (wn * 64 + (lane & 15)) * 16;

    for (int t = 0; t < kiter; ++t) {
#pragma unroll
        for (int i = 0; i < NCH; ++i)
            __builtin_amdgcn_global_load_lds(
                (const __attribute__((address_space(1))) void*)(gsrc[i] + (size_t)t * BK),
                (__attribute__((address_space(3))) void*)(smem + ldsuni[i]), 16, 0, 0);
        __syncthreads();

        f16x8 a_f[KSUB][4], b_f[KSUB][4];
#pragma unroll
        for (int ks = 0; ks < KSUB; ++ks) {
#pragma unroll
            for (int m = 0; m < 4; ++m) a_f[ks][m] = *(const f16x8*)(smem + ks * 8192 + aro + m * 256);
#pragma unroll
            for (int n = 0; n < 4; ++n) b_f[ks][n] = *(const f16x8*)(smem + ks * 8192 + bco + n * 256);
        }
#pragma unroll
        for (int ks = 0; ks < KSUB; ++ks)
#pragma unroll
            for (int m = 0; m < 4; ++m)
#pragma unroll
                for (int n = 0; n < 4; ++n)
                    acc[m][n] = __builtin_amdgcn_mfma_f32_16x16x32_f16(a_f[ks][m], b_f[ks][n],
                                                                       acc[m][n], 0, 0, 0);
        __syncthreads();
    }

    // epilogue (smem contents dead; last loop iter ended with __syncthreads)
    float* sS  = (float*)smem;           // [2][128]
    float* sS2 = (float*)smem + 256;     // [2][128]
    const int lane16 = lane & 15, lanehi = lane >> 4;
#pragma unroll
    for (int n = 0; n < 4; ++n) {
        int col = colBase + wn * 64 + n * 16 + lane16;
        float bv = bias1[col] + (bias2 ? bias2[col] : 0.f);
        float s = 0.f, s2 = 0.f;
#pragma unroll
        for (int m = 0; m < 4; ++m) {
            int row0 = rowBase + wm * 64 + m * 16 + lanehi * 4;
#pragma unroll
            for (int r = 0; r < 4; ++r) {
                float cv = acc[m][n][r] + bv;
                if constexpr (HALF_C)
                    ((_Float16*)Cv)[(size_t)(row0 + r) * ldc + col] = (_Float16)cv;
                else
                    ((float*)Cv)[(size_t)(row0 + r) * ldc + col] = cv;
                if constexpr (WEIGHTED) {
                    float w = wrow[row0 + r];
                    s += cv * w; s2 += cv * cv * w;
                } else {
                    s += cv; s2 += cv * cv;
                }
            }
        }
        if (pS) {
            s += __shfl_xor(s, 16);  s += __shfl_xor(s, 32);
            s2 += __shfl_xor(s2, 16); s2 += __shfl_xor(s2, 32);
            if (lanehi == 0) {
                int lcol = wn * 64 + n * 16 + lane16;
                sS[wm * 128 + lcol] = s;
                sS2[wm * 128 + lcol] = s2;
            }
        }
    }
    if (pS) {
        __syncthreads();
        if (tid < 128) {
            int col = colBase + tid;
            pS[(size_t)blockIdx.x * NP + col] = sS[tid] + sS[128 + tid];
            pS2[(size_t)blockIdx.x * NP + col] = sS2[tid] + sS2[128 + tid];
        }
    }
}

// ---------------- out-layer GEMM: 64x128 tile ----------------
__global__ __launch_bounds__(256, 2) void gemm_out64(
    const _Float16* __restrict__ A, int lda,
    const _Float16* __restrict__ B, int ldb,
    float* __restrict__ C, int ldc,
    const float* __restrict__ bias1, int kiter) {
    constexpr int BK = 64;
    __shared__ char smem[24576];
    const int tid = threadIdx.x;
    const int lane = tid & 63;
    const int rowBase = blockIdx.x * 64;
    const int colBase = blockIdx.y * 128;
    const int wn = tid >> 6;

    const _Float16* gsrc[6];
    int ldsuni[6];
#pragma unroll
    for (int i = 0; i < 6; ++i) {
        int w = i * 256 + tid;
        const _Float16* plane;
        int off;
        if (w < 512) {
            int r = w & 63, kb = w >> 6;
            plane = A;
            off = (rowBase + r) * lda + kb * 8;
        } else {
            int v = w - 512;
            int col = v & 127, kb = v >> 7;
            plane = B;
            off = (colBase + col) * ldb + kb * 8;
        }
        gsrc[i] = plane + off;
        ldsuni[i] = (i * 256 + (tid & ~63)) * 16;
    }

    f32x4 acc[4][2];
    const f32x4 z = {0.f, 0.f, 0.f, 0.f};
#pragma unroll
    for (int m = 0; m < 4; ++m)
#pragma unroll
        for (int n = 0; n < 2; ++n) acc[m][n] = z;

    const int aro = (lane >> 4) * 1024 + (lane & 15) * 16;
    const int bco = 8192 + (lane >> 4) * 2048 + (wn * 32 + (lane & 15)) * 16;

    for (int t = 0; t < kiter; ++t) {
#pragma unroll
        for (int i = 0; i < 6; ++i)
            __builtin_amdgcn_global_load_lds(
                (const __attribute__((address_space(1))) void*)(gsrc[i] + (size_t)t * BK),
                (__attribute__((address_space(3))) void*)(smem + ldsuni[i]), 16, 0, 0);
        __syncthreads();

        f16x8 a_f[2][4], b_f[2][2];
#pragma unroll
        for (int ks = 0; ks < 2; ++ks) {
#pragma unroll
            for (int m = 0; m < 4; ++m) a_f[ks][m] = *(const f16x8*)(smem + ks * 4096 + aro + m * 256);
#pragma unroll
            for (int n = 0; n < 2; ++n) b_f[ks][n] = *(const f16x8*)(smem + ks * 8192 + bco + n * 256);
        }
#pragma unroll
        for (int ks = 0; ks < 2; ++ks)
#pragma unroll
            for (int m = 0; m < 4; ++m)
#pragma unroll
                for (int n = 0; n < 2; ++n)
                    acc[m][n] = __builtin_amdgcn_mfma_f32_16x16x32_f16(a_f[ks][m], b_f[ks][n],
                                                                       acc[m][n], 0, 0, 0);
        __syncthreads();
    }

    const int lane16 = lane & 15, lanehi = lane >> 4;
#pragma unroll
    for (int n = 0; n < 2; ++n) {
        int col = colBase + wn * 32 + n * 16 + lane16;
        float bv = bias1[col];
#pragma unroll
        for (int m = 0; m < 4; ++m) {
            int row0 = rowBase + m * 16 + lanehi * 4;
#pragma unroll
            for (int r = 0; r < 4; ++r)
                C[(size_t)(row0 + r) * ldc + col] = acc[m][n][r] + bv;
        }
    }
}

// ---------------- fused BN finalize + apply + lrelu (fp16 in, fp16 out) ----------------
// nb: number of stat partials to reduce (64 full-batch, 2 for turn-1 compact run).
__global__ __launch_bounds__(256) void bn_apply_f(
    const _Float16* __restrict__ hraw, const float* __restrict__ pS, const float* __restrict__ pS2,
    const float* __restrict__ gamma, const float* __restrict__ beta,
    _Float16* __restrict__ oh, int psjStride, int nb) {
    __shared__ float la[128], lb[128];
    const int tid = threadIdx.x;
    const int rowBase = blockIdx.x * 128;
    const int colBase = blockIdx.y * 128;
    if (tid < 128) {
        int col = colBase + tid;
        float s = 0.f;
        for (int j = 0; j < nb; ++j) s += pS[(size_t)j * psjStride + col];
        la[tid] = s;
    } else {
        int col = colBase + tid - 128;
        float s2 = 0.f;
        for (int j = 0; j < nb; ++j) s2 += pS2[(size_t)j * psjStride + col];
        lb[tid - 128] = s2;
    }
    __syncthreads();
    if (tid < 128) {
        int col = colBase + tid;
        float a = 0.f, b = 0.f;
        if (col < H) {
            float mean = la[tid] * (1.f / NROWS);
            float var = lb[tid] * (1.f / NROWS) - mean * mean;
            float inv = rsqrtf(var + EPSBN);
            a = gamma[col] * inv;
            b = beta[col] - mean * a;
        }
        la[tid] = a;
        lb[tid] = b;
    }
    __syncthreads();
    const int c8 = (tid & 15) * 8;
    float ar[8], br[8];
#pragma unroll
    for (int j = 0; j < 8; ++j) { ar[j] = la[c8 + j]; br[j] = lb[c8 + j]; }
#pragma unroll
    for (int i = 0; i < 8; ++i) {
        int row = i * 16 + (tid >> 4);
        const u16x8 v = *(const u16x8*)(hraw + (size_t)(rowBase + row) * NP + colBase + c8);
        u16x8 o;
#pragma unroll
        for (int j = 0; j < 8; ++j) {
            float x = (float)__builtin_bit_cast(_Float16, (unsigned short)v[j]);
            o[j] = __builtin_bit_cast(unsigned short, (_Float16)lrelu(ar[j] * x + br[j]));
        }
        *(u16x8*)((unsigned short*)oh + (size_t)(rowBase + row) * NP + colBase + c8) = o;
    }
}

// ---------------- fused per-turn tail (turns 2-5): softmax + loss + argmax + hints ----------------
__global__ __launch_bounds__(256) void post_turn(
    const float* __restrict__ ybuf, const uint2* __restrict__ glp,
    const unsigned char* __restrict__ gl, const unsigned char* __restrict__ sl,
    const unsigned int* __restrict__ msk, _Float16* __restrict__ hX,
    float* __restrict__ scores, int* __restrict__ solvedf, float* __restrict__ lossacc,
    const float* __restrict__ gm, float* __restrict__ dout, int turn) {
    const int r0 = blockIdx.x * 8;
    __shared__ float pk[8][132];
    __shared__ float lcon[40];
    __shared__ float wb[4][8];
    __shared__ int wi[4][8];
    __shared__ int fidx[8];
    const int tid = threadIdx.x;

    if (tid < 40) {
        int row = tid / 5, p = tid - row * 5;
        const float* yr = ybuf + (size_t)(r0 + row) * OCP + p;
        float m = -1e30f;
#pragma unroll
        for (int c = 0; c < 26; ++c) m = fmaxf(m, yr[c * 5]);
        float e[26];
        float s = 0.f;
#pragma unroll
        for (int c = 0; c < 26; ++c) { e[c] = expf(yr[c * 5] - m); s += e[c]; }
        float inv = 1.f / s;
#pragma unroll
        for (int c = 0; c < 26; ++c) pk[row][c * 5 + p] = e[c] * inv;
        lcon[tid] = logf(s) + m - yr[sl[(size_t)(r0 + row) * 8 + p] * 5];
    }
    __syncthreads();

    float bb[8];
    int ii[8];
#pragma unroll
    for (int r = 0; r < 8; ++r) { bb[r] = -1e30f; ii[r] = 1 << 30; }
    for (int g = tid; g < NG; g += 256) {
        uint2 w = glp[g];
        int o0 = w.x & 255, o1 = (w.x >> 8) & 255, o2 = (w.x >> 16) & 255,
            o3 = w.x >> 24, o4 = w.y & 255;
#pragma unroll
        for (int r = 0; r < 8; ++r) {
            float v = pk[r][o0] + pk[r][o1]; v += pk[r][o2]; v += pk[r][o3]; v += pk[r][o4];
            if (v > bb[r]) { bb[r] = v; ii[r] = g; }
        }
    }
#pragma unroll
    for (int off = 1; off < 64; off <<= 1) {
#pragma unroll
        for (int r = 0; r < 8; ++r) {
            float o = __shfl_xor(bb[r], off);
            int oi = __shfl_xor(ii[r], off);
            if (o > bb[r] || (o == bb[r] && oi < ii[r])) { bb[r] = o; ii[r] = oi; }
        }
    }
    const int wid = tid >> 6, lane = tid & 63;
    if (lane == 0) {
#pragma unroll
        for (int r = 0; r < 8; ++r) { wb[wid][r] = bb[r]; wi[wid][r] = ii[r]; }
    }
    __syncthreads();

    if (tid < 8) {
        float b = wb[0][tid]; int x = wi[0][tid];
#pragma unroll
        for (int wv = 1; wv < 4; ++wv)
            if (wb[wv][tid] > b || (wb[wv][tid] == b && wi[wv][tid] < x)) { b = wb[wv][tid]; x = wi[wv][tid]; }
        fidx[tid] = x;
        int r = r0 + tid;
        const unsigned char* q = gl + x * 8;
        const unsigned char* so = sl + (size_t)r * 8;
        unsigned int mk = msk[r];
        _Float16* hrow = hX + (size_t)r * KX;
        int allg = 1;
#pragma unroll
        for (int p = 0; p < 5; ++p) {
            int g = q[p];
            int off;
            if (g == so[p]) {
                off = g * 5 + p;
            } else {
                allg = 0;
                off = ((mk >> g) & 1u) ? (130 + g * 5 + p) : (260 + g);
            }
            hrow[off] = (_Float16)((float)hrow[off] + 1.f);
        }
        solvedf[r] = allg;
        if (allg && scores[r] > (float)(turn + 1)) scores[r] = (float)(turn + 1);
    }
    if (tid == 16 && turn >= 1) {
        float t = 0.f;
#pragma unroll
        for (int j = 0; j < 40; ++j) t += lcon[j];
        atomicAdd(lossacc, t * (1.f / (NROWS * 5)));
    }
}

// ---------------- turn-0 specials ----------------
__global__ __launch_bounds__(256) void post_turn0(
    const float* __restrict__ ybuf, const uint2* __restrict__ glp,
    const float* __restrict__ gm, float* __restrict__ dout, int* __restrict__ idx0buf) {
    __shared__ float pk[132];
    __shared__ float wb[4];
    __shared__ int wi[4];
    __shared__ int fidx;
    const int tid = threadIdx.x;
    if (tid < 5) {
        int p = tid;
        const float* yr = ybuf + p;
        float m = -1e30f;
#pragma unroll
        for (int c = 0; c < 26; ++c) m = fmaxf(m, yr[c * 5]);
        float e[26];
        float s = 0.f;
#pragma unroll
        for (int c = 0; c < 26; ++c) { e[c] = expf(yr[c * 5] - m); s += e[c]; }
        float inv = 1.f / s;
#pragma unroll
        for (int c = 0; c < 26; ++c) pk[c * 5 + p] = e[c] * inv;
    }
    __syncthreads();
    float b = -1e30f;
    int bi = 1 << 30;
    for (int g = tid; g < NG; g += 256) {
        uint2 w = glp[g];
        int o0 = w.x & 255, o1 = (w.x >> 8) & 255, o2 = (w.x >> 16) & 255,
            o3 = w.x >> 24, o4 = w.y & 255;
        float v = pk[o0] + pk[o1]; v += pk[o2]; v += pk[o3]; v += pk[o4];
        if (v > b) { b = v; bi = g; }
    }
#pragma unroll
    for (int off = 1; off < 64; off <<= 1) {
        float o = __shfl_xor(b, off);
        int oi = __shfl_xor(bi, off);
        if (o > b || (o == b && oi < bi)) { b = o; bi = oi; }
    }
    const int wid = tid >> 6, lane = tid & 63;
    if (lane == 0) { wb[wid] = b; wi[wid] = bi; }
    __syncthreads();
    if (tid == 0) {
        float bx = wb[0]; int x = wi[0];
#pragma unroll
        for (int wv = 1; wv < 4; ++wv)
            if (wb[wv] > bx || (wb[wv] == bx && wi[wv] < x)) { bx = wb[wv]; x = wi[wv]; }
        fidx = x;
        idx0buf[0] = x;
    }
    __syncthreads();
    if (tid >= 64 && tid < 64 + OC) {
        dout[3 + tid - 64] = gm[(size_t)fidx * OC + (tid - 64)];
    }
}

// turn-0 per-row hints + feedback code fb0[r] in [0,243) + counts
__global__ void hints0(const int* __restrict__ idx0buf, const unsigned char* __restrict__ gl,
                       const unsigned char* __restrict__ sl, const unsigned int* __restrict__ msk,
                       _Float16* __restrict__ hX, float* __restrict__ scores,
                       int* __restrict__ solvedf, unsigned char* __restrict__ fb0,
                       int* __restrict__ cnt243) {
    int r = blockIdx.x * 256 + threadIdx.x;
    if (r >= NROWS) return;
    int x = idx0buf[0];
    const unsigned char* q = gl + x * 8;
    const unsigned char* so = sl + (size_t)r * 8;
    unsigned int mk = msk[r];
    _Float16* hrow = hX + (size_t)r * KX;
    int allg = 1, fb = 0, p3 = 1;
#pragma unroll
    for (int p = 0; p < 5; ++p) {
        int g = q[p];
        int off, code;
        if (g == so[p]) {
            off = g * 5 + p; code = 0;
        } else {
            allg = 0;
            if ((mk >> g) & 1u) { off = 130 + g * 5 + p; code = 1; }
            else { off = 260 + g; code = 2; }
        }
        hrow[off] = (_Float16)((float)hrow[off] + 1.f);
        fb += code * p3;
        p3 *= 3;
    }
    solvedf[r] = allg;
    if (allg && scores[r] > 1.f) scores[r] = 1.f;
    fb0[r] = (unsigned char)fb;
    atomicAdd(&cnt243[fb], 1);
}

// synthesize the 243 turn-1 state rows (rows 243..255 zero, weight 0)
__global__ void synth243(const int* __restrict__ idx0buf, const unsigned char* __restrict__ gl,
                         const int* __restrict__ cnt243, _Float16* __restrict__ hXc,
                         float* __restrict__ w243) {
    int t = threadIdx.x;  // 256
    _Float16* row = hXc + (size_t)t * KX;
    for (int c = 0; c < KX; ++c) row[c] = (_Float16)0.f;
    w243[t] = (t < 243) ? (float)cnt243[t] : 0.f;
    if (t < 243) {
        int x = idx0buf[0];
        int v = t;
#pragma unroll
        for (int p = 0; p < 5; ++p) {
            int d = v % 3; v /= 3;
            int g = gl[x * 8 + p];
            int off = (d == 0) ? (g * 5 + p) : (d == 1) ? (130 + g * 5 + p) : (260 + g);
            row[off] = (_Float16)((float)row[off] + 1.f);
        }
    }
}

// turn-1 compact argmax: per state row, vocab argmax + logZ sum
__global__ __launch_bounds__(256) void post_turn_t1(
    const float* __restrict__ ybuf, const uint2* __restrict__ glp,
    float* __restrict__ logZ243, int* __restrict__ gidx243) {
    const int r0 = blockIdx.x * 8;
    __shared__ float pk[8][132];
    __shared__ float lcon[40];
    __shared__ float wb[4][8];
    __shared__ int wi[4][8];
    const int tid = threadIdx.x;

    if (tid < 40) {
        int row = tid / 5, p = tid - row * 5;
        const float* yr = ybuf + (size_t)(r0 + row) * OCP + p;
        float m = -1e30f;
#pragma unroll
        for (int c = 0; c < 26; ++c) m = fmaxf(m, yr[c * 5]);
        float e[26];
        float s = 0.f;
#pragma unroll
        for (int c = 0; c < 26; ++c) { e[c] = expf(yr[c * 5] - m); s += e[c]; }
        float inv = 1.f / s;
#pragma unroll
        for (int c = 0; c < 26; ++c) pk[row][c * 5 + p] = e[c] * inv;
        lcon[tid] = logf(s) + m;
    }
    __syncthreads();

    float bb[8];
    int ii[8];
#pragma unroll
    for (int r = 0; r < 8; ++r) { bb[r] = -1e30f; ii[r] = 1 << 30; }
    for (int g = tid; g < NG; g += 256) {
        uint2 w = glp[g];
        int o0 = w.x & 255, o1 = (w.x >> 8) & 255, o2 = (w.x >> 16) & 255,
            o3 = w.x >> 24, o4 = w.y & 255;
#pragma unroll
        for (int r = 0; r < 8; ++r) {
            float v = pk[r][o0] + pk[r][o1]; v += pk[r][o2]; v += pk[r][o3]; v += pk[r][o4];
            if (v > bb[r]) { bb[r] = v; ii[r] = g; }
        }
    }
#pragma unroll
    for (int off = 1; off < 64; off <<= 1) {
#pragma unroll
        for (int r = 0; r < 8; ++r) {
            float o = __shfl_xor(bb[r], off);
            int oi = __shfl_xor(ii[r], off);
            if (o > bb[r] || (o == bb[r] && oi < ii[r])) { bb[r] = o; ii[r] = oi; }
        }
    }
    const int wid = tid >> 6, lane = tid & 63;
    if (lane == 0) {
#pragma unroll
        for (int r = 0; r < 8; ++r) { wb[wid][r] = bb[r]; wi[wid][r] = ii[r]; }
    }
    __syncthreads();
    if (tid < 8) {
        float b = wb[0][tid]; int x = wi[0][tid];
#pragma unroll
        for (int wv = 1; wv < 4; ++wv)
            if (wb[wv][tid] > b || (wb[wv][tid] == b && wi[wv][tid] < x)) { b = wb[wv][tid]; x = wi[wv][tid]; }
        gidx243[r0 + tid] = x;
        float lz = lcon[tid * 5];
#pragma unroll
        for (int j = 1; j < 5; ++j) lz += lcon[tid * 5 + j];
        logZ243[r0 + tid] = lz;
    }
}

// turn-1 scatter: per-row hint update from shared per-state guess + loss
__global__ void scatter_t1(const unsigned char* __restrict__ fb0, const int* __restrict__ gidx243,
                           const float* __restrict__ logZ243, const float* __restrict__ ybuf,
                           const unsigned char* __restrict__ gl, const unsigned char* __restrict__ sl,
                           const unsigned int* __restrict__ msk, _Float16* __restrict__ hX,
                           float* __restrict__ scores, int* __restrict__ solvedf,
                           float* __restrict__ lossacc) {
    int r = blockIdx.x * 256 + threadIdx.x;
    const int tid = threadIdx.x;
    int fb = fb0[r];
    int x = gidx243[fb];
    const unsigned char* q = gl + x * 8;
    const unsigned char* so = sl + (size_t)r * 8;
    unsigned int mk = msk[r];
    _Float16* hrow = hX + (size_t)r * KX;
    int allg = 1;
    const float* yf = ybuf + (size_t)fb * OCP;
    float l = logZ243[fb];
#pragma unroll
    for (int p = 0; p < 5; ++p) {
        int g = q[p];
        int off;
        if (g == so[p]) {
            off = g * 5 + p;
        } else {
            allg = 0;
            off = ((mk >> g) & 1u) ? (130 + g * 5 + p) : (260 + g);
        }
        hrow[off] = (_Float16)((float)hrow[off] + 1.f);
        l -= yf[so[p] * 5 + p];
    }
    solvedf[r] = allg;
    if (allg && scores[r] > 2.f) scores[r] = 2.f;
    __shared__ float red[256];
    red[tid] = l;
    __syncthreads();
    for (int off = 128; off > 0; off >>= 1) {
        if (tid < off) red[tid] += red[tid + off];
        __syncthreads();
    }
    if (tid == 0) atomicAdd(lossacc, red[0] * (1.f / (NROWS * 5)));
}

__global__ void final_reduce(const float* __restrict__ scores, const int* __restrict__ solvedf,
                             const float* __restrict__ lossacc, float* __restrict__ dout) {
    __shared__ float rs[256];
    __shared__ int ri[256];
    int tid = threadIdx.x;
    float s = 0.f;
    int c = 0;
    for (int r = tid; r < NROWS; r += 256) { s += scores[r]; c += solvedf[r]; }
    rs[tid] = s; ri[tid] = c;
    __syncthreads();
    for (int off = 128; off > 0; off >>= 1) {
        if (tid < off) { rs[tid] += rs[tid + off]; ri[tid] += ri[tid + off]; }
        __syncthreads();
    }
    if (tid == 0) {
        dout[0] = lossacc[0];
        dout[1] = rs[0];
        dout[2] = (float)ri[0];
    }
}

// ---------------- launch ----------------
extern "C" void kernel_launch(void* const* d_in, const int* in_sizes, int n_in,
                              void* d_out, int out_size, void* d_ws, size_t ws_size,
                              hipStream_t stream) {
    const float* sols   = (const float*)d_in[0];
    const float* gm     = (const float*)d_in[1];
    const float* W0     = (const float*)d_in[2];
    const float* b0     = (const float*)d_in[3];
    const float* gammas = (const float*)d_in[4];
    const float* betas  = (const float*)d_in[5];
    const float* Wh     = (const float*)d_in[6];
    const float* bh     = (const float*)d_in[7];
    const float* Wout   = (const float*)d_in[8];
    const float* bout   = (const float*)d_in[9];
    float* dout = (float*)d_out;

    char* p = (char*)d_ws;
    auto alloc = [&](size_t bytes) { void* r = (void*)p; p += (bytes + 255) & ~(size_t)255; return r; };
    _Float16* hX   = (_Float16*)alloc((size_t)NROWS * KX * 2);
    _Float16* hA   = (_Float16*)alloc((size_t)NROWS * NP * 2);
    _Float16* hraw = (_Float16*)alloc((size_t)NROWS * NP * 2);
    float* ybuf    = (float*)alloc((size_t)NROWS * OCP * 4);
    _Float16* B0T = (_Float16*)alloc((size_t)NP * KX * 2);
    _Float16* WhT = (_Float16*)alloc((size_t)3 * NP * NP * 2);
    _Float16* BoT = (_Float16*)alloc((size_t)OCP * NP * 2);
    float* b0p   = (float*)alloc(NP * 4);
    float* w0t   = (float*)alloc(6 * NP * 4);
    float* bhp   = (float*)alloc(3 * NP * 4);
    float* boutp = (float*)alloc(OCP * 4);
    float* pS    = (float*)alloc((size_t)MBLK * NP * 4);
    float* pS2   = (float*)alloc((size_t)MBLK * NP * 4);
    float* scores  = (float*)alloc(NROWS * 4);
    float* lossacc = (float*)alloc(256);
    int* solvedf = (int*)alloc(NROWS * 4);
    int* idx0buf = (int*)alloc(256);
    int* cnt243  = (int*)alloc(256 * 4);
    float* w243  = (float*)alloc(256 * 4);
    int* gidx243 = (int*)alloc(256 * 4);
    float* logZ243 = (float*)alloc(256 * 4);
    unsigned char* fb0 = (unsigned char*)alloc(NROWS);
    _Float16* hXc = (_Float16*)alloc((size_t)256 * KX * 2);
    unsigned char* gl = (unsigned char*)alloc(NG * 8);
    uint2* glp = (uint2*)alloc(NG * 8);
    unsigned char* sl = (unsigned char*)alloc(NROWS * 8);
    unsigned int* msk = (unsigned int*)alloc(NROWS * 4);

    // ---- prep ----
    transpose_f16<<<dim3(KX / 32, NP / 32), dim3(32, 8), 0, stream>>>(W0, 286, H, H, B0T, KX, NP);
    for (int l = 0; l < 3; ++l)
        transpose_f16<<<dim3(NP / 32, NP / 32), dim3(32, 8), 0, stream>>>(
            Wh + (size_t)l * H * H, H, H, H, WhT + (size_t)l * NP * NP, NP, NP);
    transpose_f16<<<dim3(NP / 32, OCP / 32), dim3(32, 8), 0, stream>>>(Wout, H, OC, OC, BoT, NP, OCP);
    prep_bias<<<41, 256, 0, stream>>>(W0, b0, bh, bout, b0p, w0t, bhp, boutp);
    prep_guess_letters<<<(NG + 255) / 256, 256, 0, stream>>>(gm, gl, glp);
    prep_sol_letters<<<(NROWS + 255) / 256, 256, 0, stream>>>(sols, sl, msk);
    init_state<<<(NROWS * KX + 255) / 256, 256, 0, stream>>>((unsigned short*)hX, scores, solvedf,
                                                             lossacc, cnt243);

    for (int t = 0; t < 6; ++t) {
        // grid scale: turn0 -> 1 row-block (all rows identical), turn1 -> 2 row-blocks (243 states)
        const int mg = (t == 0) ? 1 : (t == 1) ? 2 : MBLK;
        const int psStride = (t == 0) ? 0 : NP;
        const int nb = (t == 1) ? 2 : MBLK;
        const _Float16* Ain = (t == 1) ? hXc : hX;

        if (t == 1)
            synth243<<<1, 256, 0, stream>>>(idx0buf, gl, cnt243, hXc, w243);

        if (t == 1) {
            gemm_f16<32, true, true><<<dim3(mg, NP / 128), 256, 0, stream>>>(
                Ain, KX, B0T, KX, hraw, NP, b0p, w0t + t * NP, KX / 32, pS, pS2, w243);
        } else {
            gemm_f16<32, true, false><<<dim3(mg, NP / 128), 256, 0, stream>>>(
                Ain, KX, B0T, KX, hraw, NP, b0p, w0t + t * NP, KX / 32, pS, pS2, nullptr);
        }
        for (int l = 0; l < 4; ++l) {
            bn_apply_f<<<dim3(mg, NP / 128), 256, 0, stream>>>(
                hraw, pS, pS2, gammas + (size_t)l * H, betas + (size_t)l * H, hA, psStride, nb);
            if (l < 3) {
                if (t == 1) {
                    gemm_f16<64, true, true><<<dim3(mg, NP / 128), 256, 0, stream>>>(
                        hA, NP, WhT + (size_t)l * NP * NP, NP, hraw, NP, bhp + l * NP, nullptr,
                        NP / 64, pS, pS2, w243);
                } else {
                    gemm_f16<64, true, false><<<dim3(mg, NP / 128), 256, 0, stream>>>(
                        hA, NP, WhT + (size_t)l * NP * NP, NP, hraw, NP, bhp + l * NP, nullptr,
                        NP / 64, pS, pS2, nullptr);
                }
            } else {
                gemm_out64<<<dim3(mg * 2, OCP / 128), 256, 0, stream>>>(
                    hA, NP, BoT, NP, ybuf, OCP, boutp, NP / 64);
            }
        }
        if (t == 0) {
            post_turn0<<<1, 256, 0, stream>>>(ybuf, glp, gm, dout, idx0buf);
            hints0<<<NROWS / 256, 256, 0, stream>>>(idx0buf, gl, sl, msk, hX, scores, solvedf,
                                                    fb0, cnt243);
        } else if (t == 1) {
            post_turn_t1<<<31, 256, 0, stream>>>(ybuf, glp, logZ243, gidx243);
            scatter_t1<<<NROWS / 256, 256, 0, stream>>>(fb0, gidx243, logZ243, ybuf, gl, sl, msk,
                                                        hX, scores, solvedf, lossacc);
        } else {
            post_turn<<<NROWS / 8, 256, 0, stream>>>(ybuf, glp, gl, sl, msk, hX, scores, solvedf,
                                                     lossacc, gm, dout, t);
        }
    }
    final_reduce<<<1, 256, 0, stream>>>(scores, solvedf, lossacc, dout);
}

// Round 17
// 1445.998 us; speedup vs baseline: 1.1245x; 1.1245x over previous
//
#include <hip/hip_runtime.h>

#define NROWS 8192
#define NG    12972
#define H     1000
#define NP    1024   // padded hidden width
#define KX    288    // padded hints width (multiple of 32)
#define OCP   256    // padded output cols
#define OC    130
#define EPSBN 1e-5f
#define MBLK  (NROWS / 128)   // 64 row-blocks => 64 stat partials

typedef __attribute__((ext_vector_type(8))) _Float16 f16x8;
typedef __attribute__((ext_vector_type(8))) unsigned short u16x8;
typedef __attribute__((ext_vector_type(4))) float f32x4;

__device__ __forceinline__ float lrelu(float x) { return x >= 0.f ? x : 0.2f * x; }

// ---------------- prep: transpose fp32 -> fp16, B^T layout ----------------
__global__ void transpose_f16(const float* __restrict__ src, int R, int C, int srcStride,
                              _Float16* __restrict__ dst, int Rp, int Cp) {
    __shared__ float tile[32][33];
    int k0 = blockIdx.x * 32;
    int n0 = blockIdx.y * 32;
    int tx = threadIdx.x, ty = threadIdx.y;  // 32 x 8
#pragma unroll
    for (int i = 0; i < 32; i += 8) {
        int k = k0 + ty + i, n = n0 + tx;
        tile[ty + i][tx] = (k < R && n < C) ? src[(size_t)k * srcStride + n] : 0.f;
    }
    __syncthreads();
#pragma unroll
    for (int i = 0; i < 32; i += 8) {
        int n = n0 + ty + i, k = k0 + tx;
        if (n < Cp && k < Rp) dst[(size_t)n * Rp + k] = (_Float16)tile[tx][ty + i];
    }
}

__global__ void prep_bias(const float* __restrict__ W0, const float* __restrict__ b0,
                          const float* __restrict__ bh, const float* __restrict__ bout,
                          float* __restrict__ b0p, float* __restrict__ w0t,
                          float* __restrict__ bhp, float* __restrict__ boutp) {
    int i = blockIdx.x * 256 + threadIdx.x;
    if (i < 1024) { b0p[i] = (i < H) ? b0[i] : 0.f; return; }
    i -= 1024;
    if (i < 6 * 1024) {
        int t = i >> 10, n = i & 1023;
        w0t[i] = (n < H) ? W0[(size_t)(286 + t) * H + n] : 0.f;
        return;
    }
    i -= 6 * 1024;
    if (i < 3 * 1024) {
        int l = i >> 10, n = i & 1023;
        bhp[i] = (n < H) ? bh[l * H + n] : 0.f;
        return;
    }
    i -= 3 * 1024;
    if (i < OCP) { boutp[i] = (i < OC) ? bout[i] : 0.f; }
}

// gl: letters (for hint update). glp: packed softmax offsets letter*5+p (5 bytes in uint2).
__global__ void prep_guess_letters(const float* __restrict__ gm, unsigned char* __restrict__ gl,
                                   uint2* __restrict__ glp) {
    int g = blockIdx.x * blockDim.x + threadIdx.x;
    if (g >= NG) return;
    unsigned off[5];
    for (int p = 0; p < 5; ++p) {
        int letter = 0;
        for (int c = 0; c < 26; ++c)
            if (gm[(size_t)g * 130 + c * 5 + p] > 0.5f) { letter = c; break; }
        gl[g * 8 + p] = (unsigned char)letter;
        off[p] = (unsigned)(letter * 5 + p);
    }
    gl[g * 8 + 5] = gl[g * 8 + 6] = gl[g * 8 + 7] = 0;
    glp[g] = make_uint2(off[0] | (off[1] << 8) | (off[2] << 16) | (off[3] << 24), off[4]);
}

__global__ void prep_sol_letters(const float* __restrict__ sols, unsigned char* __restrict__ sl,
                                 unsigned int* __restrict__ msk) {
    int r = blockIdx.x * blockDim.x + threadIdx.x;
    if (r >= NROWS) return;
    unsigned int m = 0;
    for (int p = 0; p < 5; ++p) {
        int letter = 0;
        for (int c = 0; c < 26; ++c)
            if (sols[(size_t)r * 130 + c * 5 + p] > 0.5f) { letter = c; break; }
        sl[r * 8 + p] = (unsigned char)letter;
        m |= 1u << letter;
    }
    sl[r * 8 + 5] = sl[r * 8 + 6] = sl[r * 8 + 7] = 0;
    msk[r] = m;
}

__global__ void init_state(unsigned short* __restrict__ hX, float* __restrict__ scores,
                           int* __restrict__ solvedf, float* __restrict__ lossacc) {
    int i = blockIdx.x * blockDim.x + threadIdx.x;
    if (i < NROWS * KX) hX[i] = 0;
    if (i < NROWS) { scores[i] = 7.f; solvedf[i] = 0; }
    if (i == 0) lossacc[0] = 0.f;
}

// ---------------- GEMM fp16: C = A*B^T + bias, fused column stats ----------------
// 128x128 tile, 4 waves (2x2), templated BK, single LDS buffer, global_load_lds staging.
template <int BK, bool HALF_C>
__global__ __launch_bounds__(256, 2) void gemm_f16(
    const _Float16* __restrict__ A, int lda,
    const _Float16* __restrict__ B, int ldb,
    void* __restrict__ Cv, int ldc,
    const float* __restrict__ bias1, const float* __restrict__ bias2, int kiter,
    float* __restrict__ pS, float* __restrict__ pS2) {
    constexpr int NCH = BK / 8;
    constexpr int ABYTES = 256 * BK;
    constexpr int KSUB = BK / 32;
    constexpr int AW = 16 * BK;
    __shared__ char smem[512 * BK];
    const int tid = threadIdx.x;
    const int lane = tid & 63;
    const int rowBase = blockIdx.x * 128;
    const int colBase = blockIdx.y * 128;
    const int wm = (tid >> 6) & 1;
    const int wn = tid >> 7;

    const _Float16* gsrc[NCH];
    int ldsuni[NCH];
#pragma unroll
    for (int i = 0; i < NCH; ++i) {
        int w = i * 256 + tid;
        const _Float16* plane;
        int off;
        if (w < AW) {
            int r = w & 127, kb = w >> 7;
            plane = A;
            off = (rowBase + r) * lda + kb * 8;
        } else {
            int v = w - AW;
            int col = v & 127, kb = v >> 7;
            plane = B;
            off = (colBase + col) * ldb + kb * 8;
        }
        gsrc[i] = plane + off;
        ldsuni[i] = (i * 256 + (tid & ~63)) * 16;
    }

    f32x4 acc[4][4];
    const f32x4 z = {0.f, 0.f, 0.f, 0.f};
#pragma unroll
    for (int m = 0; m < 4; ++m)
#pragma unroll
        for (int n = 0; n < 4; ++n) acc[m][n] = z;

    const int aro = (lane >> 4) * 2048 + (wm * 64 + (lane & 15)) * 16;
    const int bco = ABYTES + (lane >> 4) * 2048 + (wn * 64 + (lane & 15)) * 16;

    for (int t = 0; t < kiter; ++t) {
#pragma unroll
        for (int i = 0; i < NCH; ++i)
            __builtin_amdgcn_global_load_lds(
                (const __attribute__((address_space(1))) void*)(gsrc[i] + (size_t)t * BK),
                (__attribute__((address_space(3))) void*)(smem + ldsuni[i]), 16, 0, 0);
        __syncthreads();

        f16x8 a_f[KSUB][4], b_f[KSUB][4];
#pragma unroll
        for (int ks = 0; ks < KSUB; ++ks) {
#pragma unroll
            for (int m = 0; m < 4; ++m) a_f[ks][m] = *(const f16x8*)(smem + ks * 8192 + aro + m * 256);
#pragma unroll
            for (int n = 0; n < 4; ++n) b_f[ks][n] = *(const f16x8*)(smem + ks * 8192 + bco + n * 256);
        }
#pragma unroll
        for (int ks = 0; ks < KSUB; ++ks)
#pragma unroll
            for (int m = 0; m < 4; ++m)
#pragma unroll
                for (int n = 0; n < 4; ++n)
                    acc[m][n] = __builtin_amdgcn_mfma_f32_16x16x32_f16(a_f[ks][m], b_f[ks][n],
                                                                       acc[m][n], 0, 0, 0);
        __syncthreads();
    }

    // epilogue (smem contents dead; last loop iter ended with __syncthreads)
    float* sS  = (float*)smem;           // [2][128]
    float* sS2 = (float*)smem + 256;     // [2][128]
    const int lane16 = lane & 15, lanehi = lane >> 4;
#pragma unroll
    for (int n = 0; n < 4; ++n) {
        int col = colBase + wn * 64 + n * 16 + lane16;
        float bv = bias1[col] + (bias2 ? bias2[col] : 0.f);
        float s = 0.f, s2 = 0.f;
#pragma unroll
        for (int m = 0; m < 4; ++m) {
            int row0 = rowBase + wm * 64 + m * 16 + lanehi * 4;
#pragma unroll
            for (int r = 0; r < 4; ++r) {
                float cv = acc[m][n][r] + bv;
                if constexpr (HALF_C)
                    ((_Float16*)Cv)[(size_t)(row0 + r) * ldc + col] = (_Float16)cv;
                else
                    ((float*)Cv)[(size_t)(row0 + r) * ldc + col] = cv;
                s += cv; s2 += cv * cv;
            }
        }
        if (pS) {
            s += __shfl_xor(s, 16);  s += __shfl_xor(s, 32);
            s2 += __shfl_xor(s2, 16); s2 += __shfl_xor(s2, 32);
            if (lanehi == 0) {
                int lcol = wn * 64 + n * 16 + lane16;
                sS[wm * 128 + lcol] = s;
                sS2[wm * 128 + lcol] = s2;
            }
        }
    }
    if (pS) {
        __syncthreads();
        if (tid < 128) {
            int col = colBase + tid;
            pS[(size_t)blockIdx.x * NP + col] = sS[tid] + sS[128 + tid];
            pS2[(size_t)blockIdx.x * NP + col] = sS2[tid] + sS2[128 + tid];
        }
    }
}

// ---------------- out-layer GEMM: 64x128 tile -> 256 blocks (1/CU, no idle CUs) ----------------
__global__ __launch_bounds__(256, 2) void gemm_out64(
    const _Float16* __restrict__ A, int lda,
    const _Float16* __restrict__ B, int ldb,
    float* __restrict__ C, int ldc,
    const float* __restrict__ bias1, int kiter) {
    constexpr int BK = 64;
    __shared__ char smem[24576];   // A [kb8][row64][16B] = 8KB ; B [kb8][col128][16B] = 16KB
    const int tid = threadIdx.x;
    const int lane = tid & 63;
    const int rowBase = blockIdx.x * 64;
    const int colBase = blockIdx.y * 128;
    const int wn = tid >> 6;

    const _Float16* gsrc[6];
    int ldsuni[6];
#pragma unroll
    for (int i = 0; i < 6; ++i) {
        int w = i * 256 + tid;
        const _Float16* plane;
        int off;
        if (w < 512) {
            int r = w & 63, kb = w >> 6;
            plane = A;
            off = (rowBase + r) * lda + kb * 8;
        } else {
            int v = w - 512;
            int col = v & 127, kb = v >> 7;
            plane = B;
            off = (colBase + col) * ldb + kb * 8;
        }
        gsrc[i] = plane + off;
        ldsuni[i] = (i * 256 + (tid & ~63)) * 16;
    }

    f32x4 acc[4][2];
    const f32x4 z = {0.f, 0.f, 0.f, 0.f};
#pragma unroll
    for (int m = 0; m < 4; ++m)
#pragma unroll
        for (int n = 0; n < 2; ++n) acc[m][n] = z;

    const int aro = (lane >> 4) * 1024 + (lane & 15) * 16;
    const int bco = 8192 + (lane >> 4) * 2048 + (wn * 32 + (lane & 15)) * 16;

    for (int t = 0; t < kiter; ++t) {
#pragma unroll
        for (int i = 0; i < 6; ++i)
            __builtin_amdgcn_global_load_lds(
                (const __attribute__((address_space(1))) void*)(gsrc[i] + (size_t)t * BK),
                (__attribute__((address_space(3))) void*)(smem + ldsuni[i]), 16, 0, 0);
        __syncthreads();

        f16x8 a_f[2][4], b_f[2][2];
#pragma unroll
        for (int ks = 0; ks < 2; ++ks) {
#pragma unroll
            for (int m = 0; m < 4; ++m) a_f[ks][m] = *(const f16x8*)(smem + ks * 4096 + aro + m * 256);
#pragma unroll
            for (int n = 0; n < 2; ++n) b_f[ks][n] = *(const f16x8*)(smem + ks * 8192 + bco + n * 256);
        }
#pragma unroll
        for (int ks = 0; ks < 2; ++ks)
#pragma unroll
            for (int m = 0; m < 4; ++m)
#pragma unroll
                for (int n = 0; n < 2; ++n)
                    acc[m][n] = __builtin_amdgcn_mfma_f32_16x16x32_f16(a_f[ks][m], b_f[ks][n],
                                                                       acc[m][n], 0, 0, 0);
        __syncthreads();
    }

    const int lane16 = lane & 15, lanehi = lane >> 4;
#pragma unroll
    for (int n = 0; n < 2; ++n) {
        int col = colBase + wn * 32 + n * 16 + lane16;
        float bv = bias1[col];
#pragma unroll
        for (int m = 0; m < 4; ++m) {
            int row0 = rowBase + m * 16 + lanehi * 4;
#pragma unroll
            for (int r = 0; r < 4; ++r)
                C[(size_t)(row0 + r) * ldc + col] = acc[m][n][r] + bv;
        }
    }
}

// ---------------- fused BN finalize + apply + lrelu (fp16 in, fp16 out) ----------------
__global__ __launch_bounds__(256) void bn_apply_f(
    const _Float16* __restrict__ hraw, const float* __restrict__ pS, const float* __restrict__ pS2,
    const float* __restrict__ gamma, const float* __restrict__ beta,
    _Float16* __restrict__ oh, int psjStride) {
    __shared__ float la[128], lb[128];
    const int tid = threadIdx.x;
    const int rowBase = blockIdx.x * 128;
    const int colBase = blockIdx.y * 128;
    if (tid < 128) {
        int col = colBase + tid;
        float s = 0.f;
        for (int j = 0; j < MBLK; ++j) s += pS[(size_t)j * psjStride + col];
        la[tid] = s;
    } else {
        int col = colBase + tid - 128;
        float s2 = 0.f;
        for (int j = 0; j < MBLK; ++j) s2 += pS2[(size_t)j * psjStride + col];
        lb[tid - 128] = s2;
    }
    __syncthreads();
    if (tid < 128) {
        int col = colBase + tid;
        float a = 0.f, b = 0.f;
        if (col < H) {
            float mean = la[tid] * (1.f / NROWS);
            float var = lb[tid] * (1.f / NROWS) - mean * mean;
            float inv = rsqrtf(var + EPSBN);
            a = gamma[col] * inv;
            b = beta[col] - mean * a;
        }
        la[tid] = a;
        lb[tid] = b;
    }
    __syncthreads();
    const int c8 = (tid & 15) * 8;
    float ar[8], br[8];
#pragma unroll
    for (int j = 0; j < 8; ++j) { ar[j] = la[c8 + j]; br[j] = lb[c8 + j]; }
#pragma unroll
    for (int i = 0; i < 8; ++i) {
        int row = i * 16 + (tid >> 4);
        const u16x8 v = *(const u16x8*)(hraw + (size_t)(rowBase + row) * NP + colBase + c8);
        u16x8 o;
#pragma unroll
        for (int j = 0; j < 8; ++j) {
            float x = (float)__builtin_bit_cast(_Float16, (unsigned short)v[j]);
            o[j] = __builtin_bit_cast(unsigned short, (_Float16)lrelu(ar[j] * x + br[j]));
        }
        *(u16x8*)((unsigned short*)oh + (size_t)(rowBase + row) * NP + colBase + c8) = o;
    }
}

// ---------------- fused per-turn tail: softmax + loss + vocab argmax + hints ----------------
// 8 rows/block, SoA b32 prob tables (proven: 53K conflicts, ~58us — LDS-throughput floor).
__global__ __launch_bounds__(256) void post_turn(
    const float* __restrict__ ybuf, const uint2* __restrict__ glp,
    const unsigned char* __restrict__ gl, const unsigned char* __restrict__ sl,
    const unsigned int* __restrict__ msk, _Float16* __restrict__ hX,
    float* __restrict__ scores, int* __restrict__ solvedf, float* __restrict__ lossacc,
    const float* __restrict__ gm, float* __restrict__ dout, int turn) {
    const int r0 = blockIdx.x * 8;
    __shared__ float pk[8][132];
    __shared__ float lcon[40];
    __shared__ float wb[4][8];
    __shared__ int wi[4][8];
    __shared__ int fidx[8];
    const int tid = threadIdx.x;

    if (tid < 40) {
        int row = tid / 5, p = tid - row * 5;
        const float* yr = ybuf + (size_t)(r0 + row) * OCP + p;
        float m = -1e30f;
#pragma unroll
        for (int c = 0; c < 26; ++c) m = fmaxf(m, yr[c * 5]);
        float e[26];
        float s = 0.f;
#pragma unroll
        for (int c = 0; c < 26; ++c) { e[c] = expf(yr[c * 5] - m); s += e[c]; }
        float inv = 1.f / s;
#pragma unroll
        for (int c = 0; c < 26; ++c) pk[row][c * 5 + p] = e[c] * inv;
        lcon[tid] = logf(s) + m - yr[sl[(size_t)(r0 + row) * 8 + p] * 5];
    }
    __syncthreads();

    float bb[8];
    int ii[8];
#pragma unroll
    for (int r = 0; r < 8; ++r) { bb[r] = -1e30f; ii[r] = 1 << 30; }
    for (int g = tid; g < NG; g += 256) {
        uint2 w = glp[g];
        int o0 = w.x & 255, o1 = (w.x >> 8) & 255, o2 = (w.x >> 16) & 255,
            o3 = w.x >> 24, o4 = w.y & 255;
#pragma unroll
        for (int r = 0; r < 8; ++r) {
            float v = pk[r][o0] + pk[r][o1]; v += pk[r][o2]; v += pk[r][o3]; v += pk[r][o4];
            if (v > bb[r]) { bb[r] = v; ii[r] = g; }
        }
    }
#pragma unroll
    for (int off = 1; off < 64; off <<= 1) {
#pragma unroll
        for (int r = 0; r < 8; ++r) {
            float o = __shfl_xor(bb[r], off);
            int oi = __shfl_xor(ii[r], off);
            if (o > bb[r] || (o == bb[r] && oi < ii[r])) { bb[r] = o; ii[r] = oi; }
        }
    }
    const int wid = tid >> 6, lane = tid & 63;
    if (lane == 0) {
#pragma unroll
        for (int r = 0; r < 8; ++r) { wb[wid][r] = bb[r]; wi[wid][r] = ii[r]; }
    }
    __syncthreads();

    if (tid < 8) {
        float b = wb[0][tid]; int x = wi[0][tid];
#pragma unroll
        for (int wv = 1; wv < 4; ++wv)
            if (wb[wv][tid] > b || (wb[wv][tid] == b && wi[wv][tid] < x)) { b = wb[wv][tid]; x = wi[wv][tid]; }
        fidx[tid] = x;
        int r = r0 + tid;
        const unsigned char* q = gl + x * 8;
        const unsigned char* so = sl + (size_t)r * 8;
        unsigned int mk = msk[r];
        _Float16* hrow = hX + (size_t)r * KX;
        int allg = 1;
#pragma unroll
        for (int p = 0; p < 5; ++p) {
            int g = q[p];
            int off;
            if (g == so[p]) {
                off = g * 5 + p;
            } else {
                allg = 0;
                off = ((mk >> g) & 1u) ? (130 + g * 5 + p) : (260 + g);
            }
            hrow[off] = (_Float16)((float)hrow[off] + 1.f);
        }
        solvedf[r] = allg;
        if (allg && scores[r] > (float)(turn + 1)) scores[r] = (float)(turn + 1);
    }
    if (tid == 16 && turn >= 1) {
        float t = 0.f;
#pragma unroll
        for (int j = 0; j < 40; ++j) t += lcon[j];
        atomicAdd(lossacc, t * (1.f / (NROWS * 5)));
    }
    __syncthreads();
    if (turn == 0 && blockIdx.x == 0 && tid >= 64 && tid < 64 + OC) {
        dout[3 + tid - 64] = gm[(size_t)fidx[0] * OC + (tid - 64)];
    }
}

// ---------------- turn-0 specials: one shared argmax + per-row hint update ----------------
__global__ __launch_bounds__(256) void post_turn0(
    const float* __restrict__ ybuf, const uint2* __restrict__ glp,
    const float* __restrict__ gm, float* __restrict__ dout, int* __restrict__ idx0buf) {
    __shared__ float pk[132];
    __shared__ float wb[4];
    __shared__ int wi[4];
    __shared__ int fidx;
    const int tid = threadIdx.x;
    if (tid < 5) {
        int p = tid;
        const float* yr = ybuf + p;
        float m = -1e30f;
#pragma unroll
        for (int c = 0; c < 26; ++c) m = fmaxf(m, yr[c * 5]);
        float e[26];
        float s = 0.f;
#pragma unroll
        for (int c = 0; c < 26; ++c) { e[c] = expf(yr[c * 5] - m); s += e[c]; }
        float inv = 1.f / s;
#pragma unroll
        for (int c = 0; c < 26; ++c) pk[c * 5 + p] = e[c] * inv;
    }
    __syncthreads();
    float b = -1e30f;
    int bi = 1 << 30;
    for (int g = tid; g < NG; g += 256) {
        uint2 w = glp[g];
        int o0 = w.x & 255, o1 = (w.x >> 8) & 255, o2 = (w.x >> 16) & 255,
            o3 = w.x >> 24, o4 = w.y & 255;
        float v = pk[o0] + pk[o1]; v += pk[o2]; v += pk[o3]; v += pk[o4];
        if (v > b) { b = v; bi = g; }
    }
#pragma unroll
    for (int off = 1; off < 64; off <<= 1) {
        float o = __shfl_xor(b, off);
        int oi = __shfl_xor(bi, off);
        if (o > b || (o == b && oi < bi)) { b = o; bi = oi; }
    }
    const int wid = tid >> 6, lane = tid & 63;
    if (lane == 0) { wb[wid] = b; wi[wid] = bi; }
    __syncthreads();
    if (tid == 0) {
        float bx = wb[0]; int x = wi[0];
#pragma unroll
        for (int wv = 1; wv < 4; ++wv)
            if (wb[wv] > bx || (wb[wv] == bx && wi[wv] < x)) { bx = wb[wv]; x = wi[wv]; }
        fidx = x;
        idx0buf[0] = x;
    }
    __syncthreads();
    if (tid >= 64 && tid < 64 + OC) {
        dout[3 + tid - 64] = gm[(size_t)fidx * OC + (tid - 64)];
    }
}

__global__ void hints0(const int* __restrict__ idx0buf, const unsigned char* __restrict__ gl,
                       const unsigned char* __restrict__ sl, const unsigned int* __restrict__ msk,
                       _Float16* __restrict__ hX, float* __restrict__ scores,
                       int* __restrict__ solvedf) {
    int r = blockIdx.x * 256 + threadIdx.x;
    if (r >= NROWS) return;
    int x = idx0buf[0];
    const unsigned char* q = gl + x * 8;
    const unsigned char* so = sl + (size_t)r * 8;
    unsigned int mk = msk[r];
    _Float16* hrow = hX + (size_t)r * KX;
    int allg = 1;
#pragma unroll
    for (int p = 0; p < 5; ++p) {
        int g = q[p];
        int off;
        if (g == so[p]) {
            off = g * 5 + p;
        } else {
            allg = 0;
            off = ((mk >> g) & 1u) ? (130 + g * 5 + p) : (260 + g);
        }
        hrow[off] = (_Float16)((float)hrow[off] + 1.f);
    }
    solvedf[r] = allg;
    if (allg && scores[r] > 1.f) scores[r] = 1.f;
}

__global__ void final_reduce(const float* __restrict__ scores, const int* __restrict__ solvedf,
                             const float* __restrict__ lossacc, float* __restrict__ dout) {
    __shared__ float rs[256];
    __shared__ int ri[256];
    int tid = threadIdx.x;
    float s = 0.f;
    int c = 0;
    for (int r = tid; r < NROWS; r += 256) { s += scores[r]; c += solvedf[r]; }
    rs[tid] = s; ri[tid] = c;
    __syncthreads();
    for (int off = 128; off > 0; off >>= 1) {
        if (tid < off) { rs[tid] += rs[tid + off]; ri[tid] += ri[tid + off]; }
        __syncthreads();
    }
    if (tid == 0) {
        dout[0] = lossacc[0];
        dout[1] = rs[0];
        dout[2] = (float)ri[0];
    }
}

// ---------------- launch ----------------
extern "C" void kernel_launch(void* const* d_in, const int* in_sizes, int n_in,
                              void* d_out, int out_size, void* d_ws, size_t ws_size,
                              hipStream_t stream) {
    const float* sols   = (const float*)d_in[0];
    const float* gm     = (const float*)d_in[1];
    const float* W0     = (const float*)d_in[2];
    const float* b0     = (const float*)d_in[3];
    const float* gammas = (const float*)d_in[4];
    const float* betas  = (const float*)d_in[5];
    const float* Wh     = (const float*)d_in[6];
    const float* bh     = (const float*)d_in[7];
    const float* Wout   = (const float*)d_in[8];
    const float* bout   = (const float*)d_in[9];
    float* dout = (float*)d_out;

    char* p = (char*)d_ws;
    auto alloc = [&](size_t bytes) { void* r = (void*)p; p += (bytes + 255) & ~(size_t)255; return r; };
    _Float16* hX   = (_Float16*)alloc((size_t)NROWS * KX * 2);
    _Float16* hA   = (_Float16*)alloc((size_t)NROWS * NP * 2);
    _Float16* hraw = (_Float16*)alloc((size_t)NROWS * NP * 2);
    float* ybuf    = (float*)alloc((size_t)NROWS * OCP * 4);
    _Float16* B0T = (_Float16*)alloc((size_t)NP * KX * 2);
    _Float16* WhT = (_Float16*)alloc((size_t)3 * NP * NP * 2);
    _Float16* BoT = (_Float16*)alloc((size_t)OCP * NP * 2);
    float* b0p   = (float*)alloc(NP * 4);
    float* w0t   = (float*)alloc(6 * NP * 4);
    float* bhp   = (float*)alloc(3 * NP * 4);
    float* boutp = (float*)alloc(OCP * 4);
    float* pS    = (float*)alloc((size_t)MBLK * NP * 4);
    float* pS2   = (float*)alloc((size_t)MBLK * NP * 4);
    float* scores  = (float*)alloc(NROWS * 4);
    float* lossacc = (float*)alloc(256);
    int* solvedf = (int*)alloc(NROWS * 4);
    int* idx0buf = (int*)alloc(256);
    unsigned char* gl = (unsigned char*)alloc(NG * 8);
    uint2* glp = (uint2*)alloc(NG * 8);
    unsigned char* sl = (unsigned char*)alloc(NROWS * 8);
    unsigned int* msk = (unsigned int*)alloc(NROWS * 4);

    // ---- prep ----
    transpose_f16<<<dim3(KX / 32, NP / 32), dim3(32, 8), 0, stream>>>(W0, 286, H, H, B0T, KX, NP);
    for (int l = 0; l < 3; ++l)
        transpose_f16<<<dim3(NP / 32, NP / 32), dim3(32, 8), 0, stream>>>(
            Wh + (size_t)l * H * H, H, H, H, WhT + (size_t)l * NP * NP, NP, NP);
    transpose_f16<<<dim3(NP / 32, OCP / 32), dim3(32, 8), 0, stream>>>(Wout, H, OC, OC, BoT, NP, OCP);
    prep_bias<<<41, 256, 0, stream>>>(W0, b0, bh, bout, b0p, w0t, bhp, boutp);
    prep_guess_letters<<<(NG + 255) / 256, 256, 0, stream>>>(gm, gl, glp);
    prep_sol_letters<<<(NROWS + 255) / 256, 256, 0, stream>>>(sols, sl, msk);
    init_state<<<(NROWS * KX + 255) / 256, 256, 0, stream>>>((unsigned short*)hX, scores, solvedf, lossacc);

    for (int t = 0; t < 6; ++t) {
        const int mg = (t == 0) ? 1 : MBLK;          // turn-0: all rows identical -> 1/64 grid
        const int psStride = (t == 0) ? 0 : NP;      // turn-0: 64 equal partials == pS[0] read 64x
        // h = X @ W0 + b0 + W0[286+t]  (turn one-hot folded into bias2)
        gemm_f16<32, true><<<dim3(mg, NP / 128), 256, 0, stream>>>(
            hX, KX, B0T, KX, hraw, NP, b0p, w0t + t * NP, KX / 32, pS, pS2);
        for (int l = 0; l < 4; ++l) {
            bn_apply_f<<<dim3(mg, NP / 128), 256, 0, stream>>>(
                hraw, pS, pS2, gammas + (size_t)l * H, betas + (size_t)l * H, hA, psStride);
            if (l < 3) {
                gemm_f16<64, true><<<dim3(mg, NP / 128), 256, 0, stream>>>(
                    hA, NP, WhT + (size_t)l * NP * NP, NP, hraw, NP, bhp + l * NP, nullptr,
                    NP / 64, pS, pS2);
            } else {
                gemm_out64<<<dim3((t == 0) ? 1 : MBLK * 2, OCP / 128), 256, 0, stream>>>(
                    hA, NP, BoT, NP, ybuf, OCP, boutp, NP / 64);
            }
        }
        if (t == 0) {
            post_turn0<<<1, 256, 0, stream>>>(ybuf, glp, gm, dout, idx0buf);
            hints0<<<NROWS / 256, 256, 0, stream>>>(idx0buf, gl, sl, msk, hX, scores, solvedf);
        } else {
            post_turn<<<NROWS / 8, 256, 0, stream>>>(ybuf, glp, gl, sl, msk, hX, scores, solvedf,
                                                     lossacc, gm, dout, t);
        }
    }
    final_reduce<<<1, 256, 0, stream>>>(scores, solvedf, lossacc, dout);
}